// Round 1
// baseline (10.456 us; speedup 1.0000x reference)
//
#include <hip/hip_runtime.h>
#include <math.h>

// Problem constants (match reference.py)
#define DFOCK 2048
#define BATCH 256
#define ROWS  (2 * DFOCK)          // 4096
#define ELEMS (ROWS * BATCH)       // 1,048,576 floats per real/imag plane
#define NVEC4 (ELEMS / 4)          // 262,144 float4 threads

// out = stack([real, imag]) of diag-phase rotation:
//   n = row >> 1 ; theta = pi * angle * n
//   out_re = cos(theta)*xr - sin(theta)*xi
//   out_im = sin(theta)*xr + cos(theta)*xi
__global__ __launch_bounds__(256)
void rotation_phase_kernel(const float* __restrict__ angle,
                           const float* __restrict__ xr,
                           const float* __restrict__ xi,
                           float* __restrict__ out) {
    const int tid = blockIdx.x * blockDim.x + threadIdx.x;
    if (tid >= NVEC4) return;

    const int e   = tid << 2;        // flat float index
    const int row = e >> 8;          // e / BATCH (BATCH == 256)
    const int n   = row >> 1;        // Fock index

    // Wave-uniform phase computation in double (theta up to ~2e4 rad).
    const double ang = (double)angle[0];
    double t = ((double)M_PI) * ang * (double)n;
    const double twopi = 6.283185307179586476925286766559;
    t -= floor(t / twopi) * twopi;   // exact enough: |t| < 2^15, double has 52 bits
    double sd, cd;
    sincos(t, &sd, &cd);
    const float c = (float)cd;
    const float s = (float)sd;

    const float4 vr = *reinterpret_cast<const float4*>(xr + e);
    const float4 vi = *reinterpret_cast<const float4*>(xi + e);

    float4 orr, oii;
    orr.x = c * vr.x - s * vi.x;  oii.x = s * vr.x + c * vi.x;
    orr.y = c * vr.y - s * vi.y;  oii.y = s * vr.y + c * vi.y;
    orr.z = c * vr.z - s * vi.z;  oii.z = s * vr.z + c * vi.z;
    orr.w = c * vr.w - s * vi.w;  oii.w = s * vr.w + c * vi.w;

    *reinterpret_cast<float4*>(out + e)         = orr;   // real plane
    *reinterpret_cast<float4*>(out + ELEMS + e) = oii;   // imag plane
}

extern "C" void kernel_launch(void* const* d_in, const int* in_sizes, int n_in,
                              void* d_out, int out_size, void* d_ws, size_t ws_size,
                              hipStream_t stream) {
    // Inputs per setup_inputs(): angle (1), a (D*D, unused), x_real (2D*B), x_imag (2D*B)
    const float* angle = (const float*)d_in[0];
    const float* xr    = (const float*)d_in[2];
    const float* xi    = (const float*)d_in[3];
    float* out         = (float*)d_out;

    const int threads = 256;
    const int blocks  = (NVEC4 + threads - 1) / threads;   // 1024
    rotation_phase_kernel<<<blocks, threads, 0, stream>>>(angle, xr, xi, out);
}

// Round 2
// 10.159 us; speedup vs baseline: 1.0293x; 1.0293x over previous
//
#include <hip/hip_runtime.h>
#include <math.h>

// Problem constants (match reference.py)
#define DFOCK 2048
#define BATCH 256
#define ROWS  (2 * DFOCK)          // 4096
#define ELEMS (ROWS * BATCH)       // 1,048,576 floats per real/imag plane
#define NVEC4 (ELEMS / 4)          // 262,144 float4 threads

// Reference reduces to a diagonal phase rotation:
//   M = expm(i*pi*angle*diag(0..D-1)) -> out[row] = exp(i*theta_n) * x[row],
//   n = row>>1, theta_n = pi*angle*n.
// Hardware v_sin_f32/v_cos_f32 take REVOLUTIONS: sin(2*pi*f).
//   theta = 2*pi*rev with rev = angle*n/2 -> reduce rev mod 1 in double, then
//   two hardware transcendental ops. Chain ~20 cycles vs ~500 for double sincos.
__global__ __launch_bounds__(256)
void rotation_phase_kernel(const float* __restrict__ angle,
                           const float* __restrict__ xr,
                           const float* __restrict__ xi,
                           float* __restrict__ out) {
    const int tid = blockIdx.x * blockDim.x + threadIdx.x;
    if (tid >= NVEC4) return;

    const int e   = tid << 2;        // flat float index
    const int row = e >> 8;          // e / BATCH (BATCH == 256)
    const int n   = row >> 1;        // Fock index (wave-uniform: 1 wave = 1 row)

    // rev = angle*n/2; |rev| < 3216, double mul error ~7e-13, mod-1 via floor is
    // exact, float cast error ~6e-8 rev = 4e-7 rad. No divide, no libm sincos.
    const double ang = (double)angle[0];
    double rev = 0.5 * ang * (double)n;
    rev -= floor(rev);
    const float fr = (float)rev;     // in [0,1)

    const float s = __builtin_amdgcn_sinf(fr);   // sin(2*pi*fr)
    const float c = __builtin_amdgcn_cosf(fr);   // cos(2*pi*fr)

    const float4 vr = *reinterpret_cast<const float4*>(xr + e);
    const float4 vi = *reinterpret_cast<const float4*>(xi + e);

    float4 orr, oii;
    orr.x = c * vr.x - s * vi.x;  oii.x = s * vr.x + c * vi.x;
    orr.y = c * vr.y - s * vi.y;  oii.y = s * vr.y + c * vi.y;
    orr.z = c * vr.z - s * vi.z;  oii.z = s * vr.z + c * vi.z;
    orr.w = c * vr.w - s * vi.w;  oii.w = s * vr.w + c * vi.w;

    *reinterpret_cast<float4*>(out + e)         = orr;   // real plane
    *reinterpret_cast<float4*>(out + ELEMS + e) = oii;   // imag plane
}

extern "C" void kernel_launch(void* const* d_in, const int* in_sizes, int n_in,
                              void* d_out, int out_size, void* d_ws, size_t ws_size,
                              hipStream_t stream) {
    // Inputs per setup_inputs(): angle (1), a (D*D, unused), x_real (2D*B), x_imag (2D*B)
    const float* angle = (const float*)d_in[0];
    const float* xr    = (const float*)d_in[2];
    const float* xi    = (const float*)d_in[3];
    float* out         = (float*)d_out;

    const int threads = 256;
    const int blocks  = (NVEC4 + threads - 1) / threads;   // 1024
    rotation_phase_kernel<<<blocks, threads, 0, stream>>>(angle, xr, xi, out);
}